// Round 1
// baseline (944.180 us; speedup 1.0000x reference)
//
#include <hip/hip_runtime.h>
#include <math.h>

// Shapes: B=4, T_LEN=128, W_DIM=128 (N), EMB=16 (E), OUT_DIM=24, DILS=(2,4)
// L = 2048, T_FINAL = 122.
// Activation layout everywhere: x[b][n][t][e] contiguous as ((b*128+n)*T+t)*16+e.

#define NCH 128
#define EDIM 16
#define LDIM 2048

// ---------------- embed ----------------
// x[b,n,t,e] = vals[b,t,n]*emb_w[0,e] + f0*emb_w[1,e] + f1*emb_w[2,e] + f2*emb_w[3,e] + emb_b[e]
__global__ void k_embed(const float* __restrict__ x_in, const float* __restrict__ emb_w,
                        const float* __restrict__ emb_b, float* __restrict__ out) {
    int idx = blockIdx.x * 256 + threadIdx.x;   // total 4*128*128*16 = 1048576
    if (idx >= 4 * 128 * 128 * 16) return;
    int e = idx & 15;
    int t = (idx >> 4) & 127;
    int n = (idx >> 11) & 127;
    int b = idx >> 18;
    const float* row = x_in + (b * 128 + t) * 131;
    float val = row[n];
    float f0 = row[128], f1 = row[129], f2 = row[130];
    out[idx] = val * emb_w[e] + f0 * emb_w[16 + e] + f1 * emb_w[32 + e]
             + f2 * emb_w[48 + e] + emb_b[e];
}

// ---------------- gated block ----------------
// out[b,c,s,e] = tanh(f)*sigmoid(g) + res
// f = sum_i x[b,i,s,e]*wf[c,i,0] + x[b,i,s+d,e]*wf[c,i,1] + bf[c]   (g likewise)
// res = sum_t x[b,c,t,e]*ws[t,s] + bs[s]
__global__ void k_gated(const float* __restrict__ x, int T, int S, int d,
                        const float* __restrict__ wf, const float* __restrict__ bf,
                        const float* __restrict__ wg, const float* __restrict__ bg,
                        const float* __restrict__ ws, const float* __restrict__ bs,
                        float* __restrict__ out) {
    int s = blockIdx.x % S;
    int b = blockIdx.x / S;
    __shared__ float x0[128][16];
    __shared__ float x1[128][16];
    __shared__ float wcol[128];
    int tid = threadIdx.x;
    {
        int i = tid >> 1;
        int e0 = (tid & 1) * 8;
        const float4* p0 = reinterpret_cast<const float4*>(x + ((size_t)(b * 128 + i) * T + s) * 16 + e0);
        const float4* p1 = reinterpret_cast<const float4*>(x + ((size_t)(b * 128 + i) * T + s + d) * 16 + e0);
        float4 a = p0[0], bq = p0[1];
        float4 c = p1[0], dq = p1[1];
        x0[i][e0 + 0] = a.x; x0[i][e0 + 1] = a.y; x0[i][e0 + 2] = a.z; x0[i][e0 + 3] = a.w;
        x0[i][e0 + 4] = bq.x; x0[i][e0 + 5] = bq.y; x0[i][e0 + 6] = bq.z; x0[i][e0 + 7] = bq.w;
        x1[i][e0 + 0] = c.x; x1[i][e0 + 1] = c.y; x1[i][e0 + 2] = c.z; x1[i][e0 + 3] = c.w;
        x1[i][e0 + 4] = dq.x; x1[i][e0 + 5] = dq.y; x1[i][e0 + 6] = dq.z; x1[i][e0 + 7] = dq.w;
    }
    if (tid < T) wcol[tid] = ws[tid * S + s];
    __syncthreads();

    int e = tid & 15;
    int cb = tid >> 4;
    float bss = bs[s];
    for (int k = 0; k < 8; ++k) {
        int c = cb + k * 16;
        float f = bf[c], g = bg[c];
        const float* wfp = wf + c * 256;
        const float* wgp = wg + c * 256;
#pragma unroll 4
        for (int i = 0; i < 128; ++i) {
            float a0 = x0[i][e], a1 = x1[i][e];
            f += a0 * wfp[2 * i] + a1 * wfp[2 * i + 1];
            g += a0 * wgp[2 * i] + a1 * wgp[2 * i + 1];
        }
        float r = bss;
        const float* xp = x + ((size_t)(b * 128 + c) * T) * 16 + e;
#pragma unroll 4
        for (int t = 0; t < T; ++t) r += xp[t * 16] * wcol[t];
        float sig = 1.f / (1.f + expf(-g));
        out[((size_t)(b * 128 + c) * S + s) * 16 + e] = tanhf(f) * sig + r;
    }
}

// ---------------- attention precompute ----------------
// A[i,j] = sum_l wq[i,l]*wk[j,l];  uvc[0:128]=u=Wq·bk, uvc[128:256]=v=Wk·bq, uvc[256]=bq·bk
__global__ void k_attn_pre(const float* __restrict__ wq, const float* __restrict__ bq,
                           const float* __restrict__ wk, const float* __restrict__ bk,
                           float* __restrict__ A, float* __restrict__ uvc) {
    __shared__ float qrow[2048];
    int i = blockIdx.x;
    int tid = threadIdx.x;
    for (int k = tid; k < 2048; k += 128) qrow[k] = wq[(size_t)i * 2048 + k];
    __syncthreads();
    const float* krow = wk + (size_t)tid * 2048;
    float acc = 0.f;
#pragma unroll 4
    for (int l = 0; l < 2048; ++l) acc += qrow[l] * krow[l];
    A[i * 128 + tid] = acc;
    if (tid == 0) {
        float u = 0.f;
        for (int l = 0; l < 2048; ++l) u += qrow[l] * bk[l];
        uvc[i] = u;
    }
    if (i == 0) {
        float v = 0.f;
        for (int l = 0; l < 2048; ++l) v += krow[l] * bq[l];
        uvc[128 + tid] = v;
        if (tid == 0) {
            float c = 0.f;
            for (int l = 0; l < 2048; ++l) c += bq[l] * bk[l];
            uvc[256] = c;
        }
    }
}

// ---------------- attention (in-place) ----------------
// Per (b,t): X[e][n] = x[b,n,t,e] (16x128).
// S = (X A Xt + X·u + (X·v)t + c) * scale ; alpha = softmax_f(S)
// abar[f] = mean_e alpha[e,f]; z = abar^T X; r = z Wv + bv; x += r reshaped.
__global__ void k_attn(float* __restrict__ x, int T,
                       const float* __restrict__ A, const float* __restrict__ uvc,
                       const float* __restrict__ wv, const float* __restrict__ bv) {
    int t = blockIdx.x % T;
    int b = blockIdx.x / T;
    __shared__ float X[16][132];
    __shared__ float Y[16][132];
    __shared__ float Sm[16][17];
    __shared__ float al[16][17];
    __shared__ float ue[16], vf[16], abar[16], z[128];
    int tid = threadIdx.x;
    {
        int n = tid >> 1;
        int e0 = (tid & 1) * 8;
        const float4* p = reinterpret_cast<const float4*>(x + ((size_t)(b * 128 + n) * T + t) * 16 + e0);
        float4 a = p[0], c = p[1];
        X[e0 + 0][n] = a.x; X[e0 + 1][n] = a.y; X[e0 + 2][n] = a.z; X[e0 + 3][n] = a.w;
        X[e0 + 4][n] = c.x; X[e0 + 5][n] = c.y; X[e0 + 6][n] = c.z; X[e0 + 7][n] = c.w;
    }
    __syncthreads();
    // Y[e][i] = sum_n X[e][n]*A[n,i]
    {
        int i = tid & 127;
        int e0 = tid >> 7;
        for (int k = 0; k < 8; ++k) {
            int e = e0 + 2 * k;
            float acc = 0.f;
#pragma unroll 4
            for (int n = 0; n < 128; ++n) acc += X[e][n] * A[n * 128 + i];
            Y[e][i] = acc;
        }
    }
    if (tid < 16) {
        float a = 0.f;
        for (int n = 0; n < 128; ++n) a += X[tid][n] * uvc[n];
        ue[tid] = a;
    } else if (tid < 32) {
        int f = tid - 16;
        float a = 0.f;
        for (int n = 0; n < 128; ++n) a += X[f][n] * uvc[128 + n];
        vf[f] = a;
    }
    __syncthreads();
    // scores
    {
        int e = tid >> 4, f = tid & 15;
        float acc = uvc[256] + ue[e] + vf[f];
#pragma unroll 4
        for (int i = 0; i < 128; ++i) acc += Y[e][i] * X[f][i];
        Sm[e][f] = acc * 0.022097086912079608f;  // 1/sqrt(2048)
    }
    __syncthreads();
    if (tid < 16) {
        float m = -1e30f;
        for (int f = 0; f < 16; ++f) m = fmaxf(m, Sm[tid][f]);
        float sum = 0.f;
        for (int f = 0; f < 16; ++f) {
            float p = expf(Sm[tid][f] - m);
            al[tid][f] = p;
            sum += p;
        }
        float inv = 1.f / sum;
        for (int f = 0; f < 16; ++f) al[tid][f] *= inv;
    }
    __syncthreads();
    if (tid < 16) {
        float a = 0.f;
        for (int e = 0; e < 16; ++e) a += al[e][tid];
        abar[tid] = a * (1.f / 16.f);
    }
    __syncthreads();
    if (tid < 128) {
        float a = 0.f;
        for (int f = 0; f < 16; ++f) a += abar[f] * X[f][tid];
        z[tid] = a;
    }
    __syncthreads();
    for (int k = 0; k < 8; ++k) {
        int l = tid + 256 * k;
        float r = bv[l];
#pragma unroll 4
        for (int n = 0; n < 128; ++n) r += z[n] * wv[(size_t)n * 2048 + l];
        int n16 = l >> 4, e = l & 15;
        x[((size_t)(b * 128 + n16) * T + t) * 16 + e] = r + X[e][n16];
    }
}

// ---------------- final dec+out ----------------
// y[b,n,t] = sum_e x[b,n,t,e]*dec_w[n,e] + dec_b[n]
// out[b,o,n] = sum_t y[b,n,t]*out_w[t,o] + out_b[o]
__global__ void k_final(const float* __restrict__ x,
                        const float* __restrict__ dec_w, const float* __restrict__ dec_b,
                        const float* __restrict__ out_w, const float* __restrict__ out_b,
                        float* __restrict__ out) {
    int n = blockIdx.x & 127;
    int b = blockIdx.x >> 7;
    const int T = 122;
    __shared__ float y[128];
    int tid = threadIdx.x;
    if (tid < T) {
        const float* xp = x + ((size_t)(b * 128 + n) * T + tid) * 16;
        const float* dw = dec_w + n * 16;
        float acc = dec_b[n];
#pragma unroll
        for (int e = 0; e < 16; ++e) acc += xp[e] * dw[e];
        y[tid] = acc;
    }
    __syncthreads();
    if (tid < 24) {
        float acc = out_b[tid];
#pragma unroll 2
        for (int t = 0; t < T; ++t) acc += y[t] * out_w[t * 24 + tid];
        out[(b * 24 + tid) * 128 + n] = acc;
    }
}

extern "C" void kernel_launch(void* const* d_in, const int* in_sizes, int n_in,
                              void* d_out, int out_size, void* d_ws, size_t ws_size,
                              hipStream_t stream) {
    const float* x_in  = (const float*)d_in[0];
    const float* emb_w = (const float*)d_in[1];
    const float* emb_b = (const float*)d_in[2];
    const float* g0_wf = (const float*)d_in[3];
    const float* g0_bf = (const float*)d_in[4];
    const float* g0_wg = (const float*)d_in[5];
    const float* g0_bg = (const float*)d_in[6];
    const float* g0_ws = (const float*)d_in[7];
    const float* g0_bs = (const float*)d_in[8];
    const float* a0_wq = (const float*)d_in[9];
    const float* a0_bq = (const float*)d_in[10];
    const float* a0_wk = (const float*)d_in[11];
    const float* a0_bk = (const float*)d_in[12];
    const float* a0_wv = (const float*)d_in[13];
    const float* a0_bv = (const float*)d_in[14];
    const float* g1_wf = (const float*)d_in[15];
    const float* g1_bf = (const float*)d_in[16];
    const float* g1_wg = (const float*)d_in[17];
    const float* g1_bg = (const float*)d_in[18];
    const float* g1_ws = (const float*)d_in[19];
    const float* g1_bs = (const float*)d_in[20];
    const float* a1_wq = (const float*)d_in[21];
    const float* a1_bq = (const float*)d_in[22];
    const float* a1_wk = (const float*)d_in[23];
    const float* a1_bk = (const float*)d_in[24];
    const float* a1_wv = (const float*)d_in[25];
    const float* a1_bv = (const float*)d_in[26];
    const float* dec_w = (const float*)d_in[27];
    const float* dec_b = (const float*)d_in[28];
    const float* out_w = (const float*)d_in[29];
    const float* out_b = (const float*)d_in[30];

    float* wsf  = (float*)d_ws;
    float* buf0 = wsf;                        // 4*128*128*16 = 1048576
    float* buf1 = buf0 + 4 * 128 * 128 * 16;  // 4*128*126*16 = 1032192
    float* buf2 = buf1 + 4 * 128 * 126 * 16;  // 4*128*122*16 = 999424
    float* A0   = buf2 + 4 * 128 * 122 * 16;  // 16384
    float* A1   = A0 + 128 * 128;             // 16384
    float* uvc0 = A1 + 128 * 128;             // 257
    float* uvc1 = uvc0 + 257;                 // 257

    k_embed<<<4096, 256, 0, stream>>>(x_in, emb_w, emb_b, buf0);
    k_attn_pre<<<128, 128, 0, stream>>>(a0_wq, a0_bq, a0_wk, a0_bk, A0, uvc0);
    k_attn_pre<<<128, 128, 0, stream>>>(a1_wq, a1_bq, a1_wk, a1_bk, A1, uvc1);

    k_gated<<<4 * 126, 256, 0, stream>>>(buf0, 128, 126, 2,
                                         g0_wf, g0_bf, g0_wg, g0_bg, g0_ws, g0_bs, buf1);
    k_attn<<<4 * 126, 256, 0, stream>>>(buf1, 126, A0, uvc0, a0_wv, a0_bv);

    k_gated<<<4 * 122, 256, 0, stream>>>(buf1, 126, 122, 4,
                                         g1_wf, g1_bf, g1_wg, g1_bg, g1_ws, g1_bs, buf2);
    k_attn<<<4 * 122, 256, 0, stream>>>(buf2, 122, A1, uvc1, a1_wv, a1_bv);

    k_final<<<4 * 128, 128, 0, stream>>>(buf2, dec_w, dec_b, out_w, out_b, (float*)d_out);
}

// Round 4
// 438.387 us; speedup vs baseline: 2.1538x; 2.1538x over previous
//
#include <hip/hip_runtime.h>
#include <math.h>

// Shapes: B=4, T_LEN=128, W_DIM=128 (N), EMB=16 (E), OUT_DIM=24, DILS=(2,4)
// L = 2048, T_FINAL = 122.
// Activation layout: x[b][n][t][e] contiguous as ((b*128+n)*T+t)*16+e.

// ---------------- embed ----------------
__global__ __launch_bounds__(256) void k_embed(const float* __restrict__ x_in,
                        const float* __restrict__ emb_w,
                        const float* __restrict__ emb_b, float* __restrict__ out) {
    int idx = blockIdx.x * 256 + threadIdx.x;   // total 4*128*128*16 = 1048576
    if (idx >= 4 * 128 * 128 * 16) return;
    int e = idx & 15;
    int t = (idx >> 4) & 127;
    int n = (idx >> 11) & 127;
    int b = idx >> 18;
    const float* row = x_in + (b * 128 + t) * 131;
    float val = row[n];
    float f0 = row[128], f1 = row[129], f2 = row[130];
    out[idx] = val * emb_w[e] + f0 * emb_w[16 + e] + f1 * emb_w[32 + e]
             + f2 * emb_w[48 + e] + emb_b[e];
}

// ---------------- zero A ----------------
__global__ __launch_bounds__(256) void k_zero(float* __restrict__ p, int n4) {
    int i = blockIdx.x * 256 + threadIdx.x;
    if (i < n4) reinterpret_cast<float4*>(p)[i] = make_float4(0.f, 0.f, 0.f, 0.f);
}

// ---------------- A = Wq * Wk^T  (128x128, K=2048), K-split with atomics ----
// grid: it(4) x jt(4) x kc(16) = 256 blocks, 256 threads.
__global__ __launch_bounds__(256) void k_gemm_aat(const float* __restrict__ wq,
                                                  const float* __restrict__ wk,
                                                  float* __restrict__ A) {
    __shared__ float sq[32][129];
    __shared__ float sk[32][129];
    int bid = blockIdx.x;
    int it = bid & 3, jt = (bid >> 2) & 3, kc = bid >> 4;
    int i0 = it * 32, j0 = jt * 32, k0 = kc * 128;
    int tid = threadIdx.x;
    int row = tid >> 3, cl = tid & 7;
#pragma unroll
    for (int h = 0; h < 4; ++h) {
        int kk = (cl + 8 * h) * 4;
        float4 q = *reinterpret_cast<const float4*>(wq + (size_t)(i0 + row) * 2048 + k0 + kk);
        float4 k = *reinterpret_cast<const float4*>(wk + (size_t)(j0 + row) * 2048 + k0 + kk);
        sq[row][kk] = q.x; sq[row][kk + 1] = q.y; sq[row][kk + 2] = q.z; sq[row][kk + 3] = q.w;
        sk[row][kk] = k.x; sk[row][kk + 1] = k.y; sk[row][kk + 2] = k.z; sk[row][kk + 3] = k.w;
    }
    __syncthreads();
    int ti = tid >> 4, tj = tid & 15;
    int i = 2 * ti, j = 2 * tj;
    float a00 = 0.f, a01 = 0.f, a10 = 0.f, a11 = 0.f;
#pragma unroll 4
    for (int k = 0; k < 128; ++k) {
        float q0 = sq[i][k], q1 = sq[i + 1][k];
        float k0v = sk[j][k], k1v = sk[j + 1][k];
        a00 += q0 * k0v; a01 += q0 * k1v; a10 += q1 * k0v; a11 += q1 * k1v;
    }
    atomicAdd(&A[(i0 + i) * 128 + j0 + j], a00);
    atomicAdd(&A[(i0 + i) * 128 + j0 + j + 1], a01);
    atomicAdd(&A[(i0 + i + 1) * 128 + j0 + j], a10);
    atomicAdd(&A[(i0 + i + 1) * 128 + j0 + j + 1], a11);
}

// ---------------- uvc: u=Wq·bk, v=Wk·bq, c=bq·bk ----------------
// grid 128 blocks x 64 threads; block i handles row i.
__global__ __launch_bounds__(64) void k_uvc(const float* __restrict__ wq,
                                            const float* __restrict__ bq,
                                            const float* __restrict__ wk,
                                            const float* __restrict__ bk,
                                            float* __restrict__ uvc) {
    int i = blockIdx.x;
    int lane = threadIdx.x;
    float u = 0.f, v = 0.f, c = 0.f;
#pragma unroll
    for (int h = 0; h < 8; ++h) {
        int l0 = (lane + 64 * h) * 4;
        float4 q = *reinterpret_cast<const float4*>(wq + (size_t)i * 2048 + l0);
        float4 k = *reinterpret_cast<const float4*>(wk + (size_t)i * 2048 + l0);
        float4 bkv = *reinterpret_cast<const float4*>(bk + l0);
        float4 bqv = *reinterpret_cast<const float4*>(bq + l0);
        u += q.x * bkv.x + q.y * bkv.y + q.z * bkv.z + q.w * bkv.w;
        v += k.x * bqv.x + k.y * bqv.y + k.z * bqv.z + k.w * bqv.w;
        if (i == 0) c += bqv.x * bkv.x + bqv.y * bkv.y + bqv.z * bkv.z + bqv.w * bkv.w;
    }
#pragma unroll
    for (int off = 32; off > 0; off >>= 1) {
        u += __shfl_down(u, off);
        v += __shfl_down(v, off);
        if (i == 0) c += __shfl_down(c, off);
    }
    if (lane == 0) {
        uvc[i] = u;
        uvc[128 + i] = v;
        if (i == 0) uvc[256] = c;
    }
}

// ---------------- gated f/g ----------------
// out[b,c,s,e] = tanh(f)*sigmoid(g)   (res added by k_gated_res)
__global__ __launch_bounds__(256) void k_gated_fg(const float* __restrict__ x, int T, int S, int d,
                        const float* __restrict__ wf, const float* __restrict__ bf,
                        const float* __restrict__ wg, const float* __restrict__ bg,
                        float* __restrict__ out) {
    int s = blockIdx.x % S;
    int b = blockIdx.x / S;
    __shared__ float x0[128][16];
    __shared__ float x1[128][16];
    int tid = threadIdx.x;
    {
        int i = tid >> 1;
        int e0 = (tid & 1) * 8;
        const float4* p0 = reinterpret_cast<const float4*>(x + ((size_t)(b * 128 + i) * T + s) * 16 + e0);
        const float4* p1 = reinterpret_cast<const float4*>(x + ((size_t)(b * 128 + i) * T + s + d) * 16 + e0);
        float4 a = p0[0], bq = p0[1];
        float4 c = p1[0], dq = p1[1];
        x0[i][e0 + 0] = a.x; x0[i][e0 + 1] = a.y; x0[i][e0 + 2] = a.z; x0[i][e0 + 3] = a.w;
        x0[i][e0 + 4] = bq.x; x0[i][e0 + 5] = bq.y; x0[i][e0 + 6] = bq.z; x0[i][e0 + 7] = bq.w;
        x1[i][e0 + 0] = c.x; x1[i][e0 + 1] = c.y; x1[i][e0 + 2] = c.z; x1[i][e0 + 3] = c.w;
        x1[i][e0 + 4] = dq.x; x1[i][e0 + 5] = dq.y; x1[i][e0 + 6] = dq.z; x1[i][e0 + 7] = dq.w;
    }
    __syncthreads();

    int e = tid & 15;
    int cg = tid >> 4;          // 0..15, c = cg*8 + q
    float f[8], g[8];
#pragma unroll
    for (int q = 0; q < 8; ++q) { f[q] = bf[cg * 8 + q]; g[q] = bg[cg * 8 + q]; }
#pragma unroll 2
    for (int i = 0; i < 128; i += 2) {
        float a0 = x0[i][e], a1 = x1[i][e];
        float a0n = x0[i + 1][e], a1n = x1[i + 1][e];
#pragma unroll
        for (int q = 0; q < 8; ++q) {
            int c = cg * 8 + q;
            float4 wfv = *reinterpret_cast<const float4*>(wf + c * 256 + 2 * i);
            float4 wgv = *reinterpret_cast<const float4*>(wg + c * 256 + 2 * i);
            f[q] += a0 * wfv.x + a1 * wfv.y + a0n * wfv.z + a1n * wfv.w;
            g[q] += a0 * wgv.x + a1 * wgv.y + a0n * wgv.z + a1n * wgv.w;
        }
    }
#pragma unroll
    for (int q = 0; q < 8; ++q) {
        int c = cg * 8 + q;
        float sig = 1.f / (1.f + expf(-g[q]));
        out[((size_t)(b * 128 + c) * S + s) * 16 + e] = tanhf(f[q]) * sig;
    }
}

// ---------------- gated res: out[b,c,s,e] += sum_t x[b,c,t,e]*ws[t,s] + bs[s] ----
// grid = B*128 blocks (one per (b,c)), 256 threads (sg=tid>>4, e=tid&15), s=sg*8+q.
__global__ __launch_bounds__(256) void k_gated_res(const float* __restrict__ x, int T, int S,
                        const float* __restrict__ ws, const float* __restrict__ bs,
                        float* __restrict__ out) {
    int c = blockIdx.x & 127;
    int b = blockIdx.x >> 7;
    __shared__ float sx[128][16];
    __shared__ float sws[32][128];
    int tid = threadIdx.x;
    // stage x[b,c,:,:] (T*16 floats, contiguous)
    const float* xp = x + ((size_t)(b * 128 + c) * T) * 16;
    for (int j = tid; j < T * 16; j += 256) reinterpret_cast<float*>(sx)[j] = xp[j];

    int sg = tid >> 4, e = tid & 15;
    float r[8];
#pragma unroll
    for (int q = 0; q < 8; ++q) r[q] = 0.f;

    for (int t0 = 0; t0 < T; t0 += 32) {
        int rows = min(32, T - t0);
        __syncthreads();
        for (int j = tid; j < rows * S; j += 256) {
            int tt = j / S;
            int ss = j - tt * S;
            sws[tt][ss] = ws[(t0 + tt) * S + ss];
        }
        __syncthreads();
        for (int tt = 0; tt < rows; ++tt) {
            float xv = sx[t0 + tt][e];
            float4 w0 = *reinterpret_cast<const float4*>(&sws[tt][sg * 8]);
            float4 w1 = *reinterpret_cast<const float4*>(&sws[tt][sg * 8 + 4]);
            r[0] += xv * w0.x; r[1] += xv * w0.y; r[2] += xv * w0.z; r[3] += xv * w0.w;
            r[4] += xv * w1.x; r[5] += xv * w1.y; r[6] += xv * w1.z; r[7] += xv * w1.w;
        }
    }
#pragma unroll
    for (int q = 0; q < 8; ++q) {
        int s = sg * 8 + q;
        if (s < S) out[((size_t)(b * 128 + c) * S + s) * 16 + e] += r[q] + bs[s];
    }
}

// ---------------- attention scores -> z ----------------
// per (b,t) block: X[n][e] staged; Y=X·A; S=Y·X^T(+bias terms); softmax; abar; z -> Z.
__global__ __launch_bounds__(256) void k_attn_score(const float* __restrict__ x, int T,
                       const float* __restrict__ A, const float* __restrict__ uvc,
                       float* __restrict__ Z) {
    int t = blockIdx.x % T;
    int b = blockIdx.x / T;
    __shared__ float X[128][20];   // [n][e], pad 20
    __shared__ float Y[16][132];
    __shared__ float Sm[16][17];
    __shared__ float al[16][17];
    __shared__ float ue[16], vf[16], abar[16];
    int tid = threadIdx.x;
    {
        int n = tid >> 1;
        int e0 = (tid & 1) * 8;
        const float4* p = reinterpret_cast<const float4*>(x + ((size_t)(b * 128 + n) * T + t) * 16 + e0);
        float4 a = p[0], c = p[1];
        X[n][e0 + 0] = a.x; X[n][e0 + 1] = a.y; X[n][e0 + 2] = a.z; X[n][e0 + 3] = a.w;
        X[n][e0 + 4] = c.x; X[n][e0 + 5] = c.y; X[n][e0 + 6] = c.z; X[n][e0 + 7] = c.w;
    }
    __syncthreads();
    // Y[e][i] = sum_n X[n][e]*A[n,i]; thread: i = tid&127, eh = tid>>7 -> e = eh*8+q
    {
        int i = tid & 127, eh = tid >> 7;
        float acc[8];
#pragma unroll
        for (int q = 0; q < 8; ++q) acc[q] = 0.f;
#pragma unroll 2
        for (int n = 0; n < 128; ++n) {
            float av = A[n * 128 + i];
            float4 xa = *reinterpret_cast<const float4*>(&X[n][eh * 8]);
            float4 xb = *reinterpret_cast<const float4*>(&X[n][eh * 8 + 4]);
            acc[0] += xa.x * av; acc[1] += xa.y * av; acc[2] += xa.z * av; acc[3] += xa.w * av;
            acc[4] += xb.x * av; acc[5] += xb.y * av; acc[6] += xb.z * av; acc[7] += xb.w * av;
        }
#pragma unroll
        for (int q = 0; q < 8; ++q) Y[eh * 8 + q][i] = acc[q];
    }
    if (tid < 16) {
        float a = 0.f;
        for (int n = 0; n < 128; ++n) a += X[n][tid] * uvc[n];
        ue[tid] = a;
    } else if (tid < 32) {
        int f = tid - 16;
        float a = 0.f;
        for (int n = 0; n < 128; ++n) a += X[n][f] * uvc[128 + n];
        vf[f] = a;
    }
    __syncthreads();
    // scores
    {
        int e = tid >> 4, f = tid & 15;
        float acc = uvc[256] + ue[e] + vf[f];
#pragma unroll 4
        for (int i = 0; i < 128; ++i) acc += Y[e][i] * X[i][f];
        Sm[e][f] = acc * 0.022097086912079608f;  // 1/sqrt(2048)
    }
    __syncthreads();
    if (tid < 16) {
        float m = -1e30f;
        for (int f = 0; f < 16; ++f) m = fmaxf(m, Sm[tid][f]);
        float sum = 0.f;
        for (int f = 0; f < 16; ++f) {
            float p = expf(Sm[tid][f] - m);
            al[tid][f] = p;
            sum += p;
        }
        float inv = 1.f / sum;
        for (int f = 0; f < 16; ++f) al[tid][f] *= inv;
    }
    __syncthreads();
    if (tid < 16) {
        float a = 0.f;
        for (int e = 0; e < 16; ++e) a += al[e][tid];
        abar[tid] = a * (1.f / 16.f);
    }
    __syncthreads();
    if (tid < 128) {
        float4 x0 = *reinterpret_cast<const float4*>(&X[tid][0]);
        float4 x1 = *reinterpret_cast<const float4*>(&X[tid][4]);
        float4 x2 = *reinterpret_cast<const float4*>(&X[tid][8]);
        float4 x3 = *reinterpret_cast<const float4*>(&X[tid][12]);
        float z = x0.x * abar[0] + x0.y * abar[1] + x0.z * abar[2] + x0.w * abar[3]
                + x1.x * abar[4] + x1.y * abar[5] + x1.z * abar[6] + x1.w * abar[7]
                + x2.x * abar[8] + x2.y * abar[9] + x2.z * abar[10] + x2.w * abar[11]
                + x3.x * abar[12] + x3.y * abar[13] + x3.z * abar[14] + x3.w * abar[15];
        Z[(size_t)blockIdx.x * 128 + tid] = z;
    }
}

// ---------------- attention out: x += Z·Wv + bv (scattered) ----------------
// grid = (BT/8) * 8 blocks; m-tile 8 rows, n-tile 256 cols. 256 threads.
__global__ __launch_bounds__(256) void k_attn_out(float* __restrict__ x, int T,
                       const float* __restrict__ Z, const float* __restrict__ wv,
                       const float* __restrict__ bv) {
    int mblk = blockIdx.x >> 3;
    int nblk = blockIdx.x & 7;
    int tid = threadIdx.x;
    int l = nblk * 256 + tid;
    __shared__ float sZ[8][128];
    int m0 = mblk * 8;
    {
        float4 v = *reinterpret_cast<const float4*>(Z + (size_t)m0 * 128 + tid * 4);
        reinterpret_cast<float4*>(&sZ[0][0])[tid] = v;
    }
    __syncthreads();
    float acc[8];
#pragma unroll
    for (int mm = 0; mm < 8; ++mm) acc[mm] = 0.f;
#pragma unroll 2
    for (int n = 0; n < 128; ++n) {
        float w = wv[(size_t)n * 2048 + l];
#pragma unroll
        for (int mm = 0; mm < 8; ++mm) acc[mm] += sZ[mm][n] * w;
    }
    float bvl = bv[l];
    int n16 = l >> 4, e = l & 15;
#pragma unroll
    for (int mm = 0; mm < 8; ++mm) {
        int row = m0 + mm;
        int b = row / T;
        int t = row - b * T;
        size_t idx = ((size_t)(b * 128 + n16) * T + t) * 16 + e;
        x[idx] += acc[mm] + bvl;
    }
}

// ---------------- final dec+out ----------------
__global__ __launch_bounds__(128) void k_final(const float* __restrict__ x,
                        const float* __restrict__ dec_w, const float* __restrict__ dec_b,
                        const float* __restrict__ out_w, const float* __restrict__ out_b,
                        float* __restrict__ out) {
    int n = blockIdx.x & 127;
    int b = blockIdx.x >> 7;
    const int T = 122;
    __shared__ float y[128];
    int tid = threadIdx.x;
    if (tid < T) {
        const float* xp = x + ((size_t)(b * 128 + n) * T + tid) * 16;
        const float* dw = dec_w + n * 16;
        float acc = dec_b[n];
#pragma unroll
        for (int e = 0; e < 16; ++e) acc += xp[e] * dw[e];
        y[tid] = acc;
    }
    __syncthreads();
    if (tid < 24) {
        float acc = out_b[tid];
#pragma unroll 2
        for (int t = 0; t < 122; ++t) acc += y[t] * out_w[t * 24 + tid];
        out[(b * 24 + tid) * 128 + n] = acc;
    }
}

extern "C" void kernel_launch(void* const* d_in, const int* in_sizes, int n_in,
                              void* d_out, int out_size, void* d_ws, size_t ws_size,
                              hipStream_t stream) {
    const float* x_in  = (const float*)d_in[0];
    const float* emb_w = (const float*)d_in[1];
    const float* emb_b = (const float*)d_in[2];
    const float* g0_wf = (const float*)d_in[3];
    const float* g0_bf = (const float*)d_in[4];
    const float* g0_wg = (const float*)d_in[5];
    const float* g0_bg = (const float*)d_in[6];
    const float* g0_ws = (const float*)d_in[7];
    const float* g0_bs = (const float*)d_in[8];
    const float* a0_wq = (const float*)d_in[9];
    const float* a0_bq = (const float*)d_in[10];
    const float* a0_wk = (const float*)d_in[11];
    const float* a0_bk = (const float*)d_in[12];
    const float* a0_wv = (const float*)d_in[13];
    const float* a0_bv = (const float*)d_in[14];
    const float* g1_wf = (const float*)d_in[15];
    const float* g1_bf = (const float*)d_in[16];
    const float* g1_wg = (const float*)d_in[17];
    const float* g1_bg = (const float*)d_in[18];
    const float* g1_ws = (const float*)d_in[19];
    const float* g1_bs = (const float*)d_in[20];
    const float* a1_wq = (const float*)d_in[21];
    const float* a1_bq = (const float*)d_in[22];
    const float* a1_wk = (const float*)d_in[23];
    const float* a1_bk = (const float*)d_in[24];
    const float* a1_wv = (const float*)d_in[25];
    const float* a1_bv = (const float*)d_in[26];
    const float* dec_w = (const float*)d_in[27];
    const float* dec_b = (const float*)d_in[28];
    const float* out_w = (const float*)d_in[29];
    const float* out_b = (const float*)d_in[30];

    float* wsf  = (float*)d_ws;
    float* buf0 = wsf;                        // 1048576 (embed out; later reused as Z)
    float* buf1 = buf0 + 4 * 128 * 128 * 16;  // 1032192
    float* buf2 = buf1 + 4 * 128 * 126 * 16;  // 999424
    float* A0   = buf2 + 4 * 128 * 122 * 16;  // 16384
    float* A1   = A0 + 128 * 128;             // 16384
    float* uvc0 = A1 + 128 * 128;             // 257
    float* uvc1 = uvc0 + 257;                 // 257
    float* Z    = buf0;                       // alias: buf0 dead after gated0 consumes it

    // attention precompute
    k_zero<<<32, 256, 0, stream>>>(A0, 2 * 128 * 128 / 4);   // zeros A0 and A1 (contiguous)
    k_gemm_aat<<<256, 256, 0, stream>>>(a0_wq, a0_wk, A0);
    k_gemm_aat<<<256, 256, 0, stream>>>(a1_wq, a1_wk, A1);
    k_uvc<<<128, 64, 0, stream>>>(a0_wq, a0_bq, a0_wk, a0_bk, uvc0);
    k_uvc<<<128, 64, 0, stream>>>(a1_wq, a1_bq, a1_wk, a1_bk, uvc1);

    k_embed<<<4096, 256, 0, stream>>>(x_in, emb_w, emb_b, buf0);

    // layer 0: T=128 -> S=126
    k_gated_fg<<<4 * 126, 256, 0, stream>>>(buf0, 128, 126, 2,
                                            g0_wf, g0_bf, g0_wg, g0_bg, buf1);
    k_gated_res<<<4 * 128, 256, 0, stream>>>(buf0, 128, 126, g0_ws, g0_bs, buf1);
    k_attn_score<<<4 * 126, 256, 0, stream>>>(buf1, 126, A0, uvc0, Z);
    k_attn_out<<<(4 * 126 / 8) * 8, 256, 0, stream>>>(buf1, 126, Z, a0_wv, a0_bv);

    // layer 1: T=126 -> S=122
    k_gated_fg<<<4 * 122, 256, 0, stream>>>(buf1, 126, 122, 4,
                                            g1_wf, g1_bf, g1_wg, g1_bg, buf2);
    k_gated_res<<<4 * 128, 256, 0, stream>>>(buf1, 126, 122, g1_ws, g1_bs, buf2);
    k_attn_score<<<4 * 122, 256, 0, stream>>>(buf2, 122, A1, uvc1, Z);
    k_attn_out<<<(4 * 122 / 8) * 8, 256, 0, stream>>>(buf2, 122, Z, a1_wv, a1_bv);

    k_final<<<512, 128, 0, stream>>>(buf2, dec_w, dec_b, out_w, out_b, (float*)d_out);
}

// Round 7
// 347.652 us; speedup vs baseline: 2.7159x; 1.2610x over previous
//
#include <hip/hip_runtime.h>
#include <math.h>

// Shapes: B=4, T_LEN=128, W_DIM=128 (N), EMB=16 (E), OUT_DIM=24, DILS=(2,4)
// L = 2048, T_FINAL = 122.
// Activation layout: x[b][n][t][e] contiguous as ((b*128+n)*T+t)*16+e.

typedef __attribute__((ext_vector_type(8))) short bf16x8;
typedef __attribute__((ext_vector_type(4))) float f32x4;

__device__ inline short f2bf(float x) {   // RNE fp32 -> bf16 bits
    union { float f; unsigned u; } v; v.f = x;
    unsigned r = v.u + 0x7FFFu + ((v.u >> 16) & 1u);
    return (short)(r >> 16);
}

// ---------------- embed ----------------
__global__ __launch_bounds__(256) void k_embed(const float* __restrict__ x_in,
                        const float* __restrict__ emb_w,
                        const float* __restrict__ emb_b, float* __restrict__ out) {
    int idx = blockIdx.x * 256 + threadIdx.x;   // total 4*128*128*16 = 1048576
    if (idx >= 4 * 128 * 128 * 16) return;
    int e = idx & 15;
    int t = (idx >> 4) & 127;
    int n = (idx >> 11) & 127;
    int b = idx >> 18;
    const float* row = x_in + (b * 128 + t) * 131;
    float val = row[n];
    float f0 = row[128], f1 = row[129], f2 = row[130];
    out[idx] = val * emb_w[e] + f0 * emb_w[16 + e] + f1 * emb_w[32 + e]
             + f2 * emb_w[48 + e] + emb_b[e];
}

// ---------------- zero A ----------------
__global__ __launch_bounds__(256) void k_zero(float* __restrict__ p, int n4) {
    int i = blockIdx.x * 256 + threadIdx.x;
    if (i < n4) reinterpret_cast<float4*>(p)[i] = make_float4(0.f, 0.f, 0.f, 0.f);
}

// ---------------- A = Wq * Wk^T  (128x128, K=2048), K-split with atomics ----
__global__ __launch_bounds__(256) void k_gemm_aat(const float* __restrict__ wq,
                                                  const float* __restrict__ wk,
                                                  float* __restrict__ A) {
    __shared__ float sq[32][129];
    __shared__ float sk[32][129];
    int bid = blockIdx.x;
    int it = bid & 3, jt = (bid >> 2) & 3, kc = bid >> 4;
    int i0 = it * 32, j0 = jt * 32, k0 = kc * 128;
    int tid = threadIdx.x;
    int row = tid >> 3, cl = tid & 7;
#pragma unroll
    for (int h = 0; h < 4; ++h) {
        int kk = (cl + 8 * h) * 4;
        float4 q = *reinterpret_cast<const float4*>(wq + (size_t)(i0 + row) * 2048 + k0 + kk);
        float4 k = *reinterpret_cast<const float4*>(wk + (size_t)(j0 + row) * 2048 + k0 + kk);
        sq[row][kk] = q.x; sq[row][kk + 1] = q.y; sq[row][kk + 2] = q.z; sq[row][kk + 3] = q.w;
        sk[row][kk] = k.x; sk[row][kk + 1] = k.y; sk[row][kk + 2] = k.z; sk[row][kk + 3] = k.w;
    }
    __syncthreads();
    int ti = tid >> 4, tj = tid & 15;
    int i = 2 * ti, j = 2 * tj;
    float a00 = 0.f, a01 = 0.f, a10 = 0.f, a11 = 0.f;
#pragma unroll 4
    for (int k = 0; k < 128; ++k) {
        float q0 = sq[i][k], q1 = sq[i + 1][k];
        float k0v = sk[j][k], k1v = sk[j + 1][k];
        a00 += q0 * k0v; a01 += q0 * k1v; a10 += q1 * k0v; a11 += q1 * k1v;
    }
    atomicAdd(&A[(i0 + i) * 128 + j0 + j], a00);
    atomicAdd(&A[(i0 + i) * 128 + j0 + j + 1], a01);
    atomicAdd(&A[(i0 + i + 1) * 128 + j0 + j], a10);
    atomicAdd(&A[(i0 + i + 1) * 128 + j0 + j + 1], a11);
}

// ---------------- uvc: u=Wq·bk, v=Wk·bq, c=bq·bk ----------------
__global__ __launch_bounds__(64) void k_uvc(const float* __restrict__ wq,
                                            const float* __restrict__ bq,
                                            const float* __restrict__ wk,
                                            const float* __restrict__ bk,
                                            float* __restrict__ uvc) {
    int i = blockIdx.x;
    int lane = threadIdx.x;
    float u = 0.f, v = 0.f, c = 0.f;
#pragma unroll
    for (int h = 0; h < 8; ++h) {
        int l0 = (lane + 64 * h) * 4;
        float4 q = *reinterpret_cast<const float4*>(wq + (size_t)i * 2048 + l0);
        float4 k = *reinterpret_cast<const float4*>(wk + (size_t)i * 2048 + l0);
        float4 bkv = *reinterpret_cast<const float4*>(bk + l0);
        float4 bqv = *reinterpret_cast<const float4*>(bq + l0);
        u += q.x * bkv.x + q.y * bkv.y + q.z * bkv.z + q.w * bkv.w;
        v += k.x * bqv.x + k.y * bqv.y + k.z * bqv.z + k.w * bqv.w;
        if (i == 0) c += bqv.x * bkv.x + bqv.y * bkv.y + bqv.z * bkv.z + bqv.w * bkv.w;
    }
#pragma unroll
    for (int off = 32; off > 0; off >>= 1) {
        u += __shfl_down(u, off);
        v += __shfl_down(v, off);
        if (i == 0) c += __shfl_down(c, off);
    }
    if (lane == 0) {
        uvc[i] = u;
        uvc[128 + i] = v;
        if (i == 0) uvc[256] = c;
    }
}

// ---------------- weight pack: Wp[m][k] bf16, m<128: wf row m; m>=128: wg row m-128 ----
// wf layout (c, i, tap) row-major -> row c is already k-contiguous (k = 2i+tap).
__global__ __launch_bounds__(256) void k_wpack(const float* __restrict__ wf,
                                               const float* __restrict__ wg,
                                               unsigned short* __restrict__ Wp) {
    int gid = blockIdx.x * 256 + threadIdx.x;   // 8192 = 256 m * 32 kgroups
    int m = gid >> 5, kg = gid & 31;
    const float* src = (m < 128 ? wf + (size_t)m * 256 : wg + (size_t)(m - 128) * 256) + kg * 8;
    float4 a = *reinterpret_cast<const float4*>(src);
    float4 b = *reinterpret_cast<const float4*>(src + 4);
    bf16x8 o;
    o[0] = f2bf(a.x); o[1] = f2bf(a.y); o[2] = f2bf(a.z); o[3] = f2bf(a.w);
    o[4] = f2bf(b.x); o[5] = f2bf(b.y); o[6] = f2bf(b.z); o[7] = f2bf(b.w);
    *reinterpret_cast<bf16x8*>(Wp + (size_t)m * 256 + kg * 8) = o;
}

// ---------------- gated f/g via MFMA ----------------
// One wave per (b,s). D[e][m] = sum_k Xp[e][k] * Wp[m][k], M=16(e), N=256(f|g), K=256.
// Xp[e][k] = x[b][ i=k>>1 ][ s + (k&1)*d ][ e ]  (gathered per-lane, cvt to bf16).
// Epilogue: out[b,c,s,e] = tanh(f+bf[c]) * sigmoid(g+bg[c]).  (res added later.)
__global__ __launch_bounds__(64) void k_gated_mfma(const float* __restrict__ x,
                        int T, int S, int d,
                        const unsigned short* __restrict__ Wp,
                        const float* __restrict__ bf, const float* __restrict__ bg,
                        float* __restrict__ out) {
    int s = blockIdx.x % S;
    int b = blockIdx.x / S;
    int lane = threadIdx.x;
    int e = lane & 15, kh = lane >> 4;   // kh = 0..3
    const float* xb = x + (size_t)b * 128 * T * 16;

    f32x4 acc[16];
#pragma unroll
    for (int i = 0; i < 16; ++i) acc[i] = (f32x4){0.f, 0.f, 0.f, 0.f};

#pragma unroll
    for (int kc = 0; kc < 8; ++kc) {
        // A fragment: lane holds Xp[e][kc*32 + kh*8 + j], j=0..7
        bf16x8 aF;
#pragma unroll
        for (int j = 0; j < 8; ++j) {
            int k = kc * 32 + kh * 8 + j;
            int i = k >> 1, tap = k & 1;
            float v = xb[((size_t)i * T + s + tap * d) * 16 + e];
            aF[j] = f2bf(v);
        }
        // B fragments: lane holds Wp[m = fn*16+e][same k-range] - one 16B load each
#pragma unroll
        for (int fn = 0; fn < 16; ++fn) {
            int m = fn * 16 + e;
            bf16x8 bF = *reinterpret_cast<const bf16x8*>(Wp + (size_t)m * 256 + kc * 32 + kh * 8);
            acc[fn] = __builtin_amdgcn_mfma_f32_16x16x32_bf16(aF, bF, acc[fn], 0, 0, 0);
        }
    }

    // Epilogue: D row = (lane>>4)*4 + reg  (= e-index), col = lane&15 (= m within frag)
    int e0 = kh * 4;
#pragma unroll
    for (int fn = 0; fn < 8; ++fn) {
        int c = fn * 16 + e;          // f at frag fn, g at frag fn+8, same lane col
        float bfv = bf[c], bgv = bg[c];
        float4 o;
        {
            float fv, gv;
            fv = acc[fn][0] + bfv; gv = acc[fn + 8][0] + bgv;
            o.x = tanhf(fv) / (1.f + expf(-gv));
            fv = acc[fn][1] + bfv; gv = acc[fn + 8][1] + bgv;
            o.y = tanhf(fv) / (1.f + expf(-gv));
            fv = acc[fn][2] + bfv; gv = acc[fn + 8][2] + bgv;
            o.z = tanhf(fv) / (1.f + expf(-gv));
            fv = acc[fn][3] + bfv; gv = acc[fn + 8][3] + bgv;
            o.w = tanhf(fv) / (1.f + expf(-gv));
        }
        *reinterpret_cast<float4*>(out + (((size_t)(b * 128 + c)) * S + s) * 16 + e0) = o;
    }
}

// ---------------- gated res: out[b,c,s,e] += sum_t x[b,c,t,e]*ws[t,s] + bs[s] ----
__global__ __launch_bounds__(256) void k_gated_res(const float* __restrict__ x, int T, int S,
                        const float* __restrict__ ws, const float* __restrict__ bs,
                        float* __restrict__ out) {
    int c = blockIdx.x & 127;
    int b = blockIdx.x >> 7;
    __shared__ float sx[128][16];
    __shared__ float sws[32][128];
    int tid = threadIdx.x;
    const float* xp = x + ((size_t)(b * 128 + c) * T) * 16;
    for (int j = tid; j < T * 16; j += 256) reinterpret_cast<float*>(sx)[j] = xp[j];

    int sg = tid >> 4, e = tid & 15;
    float r[8];
#pragma unroll
    for (int q = 0; q < 8; ++q) r[q] = 0.f;

    for (int t0 = 0; t0 < T; t0 += 32) {
        int rows = min(32, T - t0);
        __syncthreads();
        for (int j = tid; j < rows * S; j += 256) {
            int tt = j / S;
            int ss = j - tt * S;
            sws[tt][ss] = ws[(t0 + tt) * S + ss];
        }
        __syncthreads();
        for (int tt = 0; tt < rows; ++tt) {
            float xv = sx[t0 + tt][e];
            float4 w0 = *reinterpret_cast<const float4*>(&sws[tt][sg * 8]);
            float4 w1 = *reinterpret_cast<const float4*>(&sws[tt][sg * 8 + 4]);
            r[0] += xv * w0.x; r[1] += xv * w0.y; r[2] += xv * w0.z; r[3] += xv * w0.w;
            r[4] += xv * w1.x; r[5] += xv * w1.y; r[6] += xv * w1.z; r[7] += xv * w1.w;
        }
    }
#pragma unroll
    for (int q = 0; q < 8; ++q) {
        int s = sg * 8 + q;
        if (s < S) out[((size_t)(b * 128 + c) * S + s) * 16 + e] += r[q] + bs[s];
    }
}

// ---------------- attention scores -> z ----------------
__global__ __launch_bounds__(256) void k_attn_score(const float* __restrict__ x, int T,
                       const float* __restrict__ A, const float* __restrict__ uvc,
                       float* __restrict__ Z) {
    int t = blockIdx.x % T;
    int b = blockIdx.x / T;
    __shared__ float X[128][20];   // [n][e], pad 20
    __shared__ float Y[16][132];
    __shared__ float Sm[16][17];
    __shared__ float al[16][17];
    __shared__ float ue[16], vf[16], abar[16];
    int tid = threadIdx.x;
    {
        int n = tid >> 1;
        int e0 = (tid & 1) * 8;
        const float4* p = reinterpret_cast<const float4*>(x + ((size_t)(b * 128 + n) * T + t) * 16 + e0);
        float4 a = p[0], c = p[1];
        X[n][e0 + 0] = a.x; X[n][e0 + 1] = a.y; X[n][e0 + 2] = a.z; X[n][e0 + 3] = a.w;
        X[n][e0 + 4] = c.x; X[n][e0 + 5] = c.y; X[n][e0 + 6] = c.z; X[n][e0 + 7] = c.w;
    }
    __syncthreads();
    {
        int i = tid & 127, eh = tid >> 7;
        float acc[8];
#pragma unroll
        for (int q = 0; q < 8; ++q) acc[q] = 0.f;
#pragma unroll 2
        for (int n = 0; n < 128; ++n) {
            float av = A[n * 128 + i];
            float4 xa = *reinterpret_cast<const float4*>(&X[n][eh * 8]);
            float4 xb = *reinterpret_cast<const float4*>(&X[n][eh * 8 + 4]);
            acc[0] += xa.x * av; acc[1] += xa.y * av; acc[2] += xa.z * av; acc[3] += xa.w * av;
            acc[4] += xb.x * av; acc[5] += xb.y * av; acc[6] += xb.z * av; acc[7] += xb.w * av;
        }
#pragma unroll
        for (int q = 0; q < 8; ++q) Y[eh * 8 + q][i] = acc[q];
    }
    if (tid < 16) {
        float a = 0.f;
        for (int n = 0; n < 128; ++n) a += X[n][tid] * uvc[n];
        ue[tid] = a;
    } else if (tid < 32) {
        int f = tid - 16;
        float a = 0.f;
        for (int n = 0; n < 128; ++n) a += X[n][f] * uvc[128 + n];
        vf[f] = a;
    }
    __syncthreads();
    {
        int e = tid >> 4, f = tid & 15;
        float acc = uvc[256] + ue[e] + vf[f];
#pragma unroll 4
        for (int i = 0; i < 128; ++i) acc += Y[e][i] * X[i][f];
        Sm[e][f] = acc * 0.022097086912079608f;  // 1/sqrt(2048)
    }
    __syncthreads();
    if (tid < 16) {
        float m = -1e30f;
        for (int f = 0; f < 16; ++f) m = fmaxf(m, Sm[tid][f]);
        float sum = 0.f;
        for (int f = 0; f < 16; ++f) {
            float p = expf(Sm[tid][f] - m);
            al[tid][f] = p;
            sum += p;
        }
        float inv = 1.f / sum;
        for (int f = 0; f < 16; ++f) al[tid][f] *= inv;
    }
    __syncthreads();
    if (tid < 16) {
        float a = 0.f;
        for (int e = 0; e < 16; ++e) a += al[e][tid];
        abar[tid] = a * (1.f / 16.f);
    }
    __syncthreads();
    if (tid < 128) {
        float4 x0 = *reinterpret_cast<const float4*>(&X[tid][0]);
        float4 x1 = *reinterpret_cast<const float4*>(&X[tid][4]);
        float4 x2 = *reinterpret_cast<const float4*>(&X[tid][8]);
        float4 x3 = *reinterpret_cast<const float4*>(&X[tid][12]);
        float z = x0.x * abar[0] + x0.y * abar[1] + x0.z * abar[2] + x0.w * abar[3]
                + x1.x * abar[4] + x1.y * abar[5] + x1.z * abar[6] + x1.w * abar[7]
                + x2.x * abar[8] + x2.y * abar[9] + x2.z * abar[10] + x2.w * abar[11]
                + x3.x * abar[12] + x3.y * abar[13] + x3.z * abar[14] + x3.w * abar[15];
        Z[(size_t)blockIdx.x * 128 + tid] = z;
    }
}

// ---------------- attention out: x += Z·Wv + bv (scattered) ----------------
__global__ __launch_bounds__(256) void k_attn_out(float* __restrict__ x, int T,
                       const float* __restrict__ Z, const float* __restrict__ wv,
                       const float* __restrict__ bv) {
    int mblk = blockIdx.x >> 3;
    int nblk = blockIdx.x & 7;
    int tid = threadIdx.x;
    int l = nblk * 256 + tid;
    __shared__ float sZ[8][128];
    int m0 = mblk * 8;
    {
        float4 v = *reinterpret_cast<const float4*>(Z + (size_t)m0 * 128 + tid * 4);
        reinterpret_cast<float4*>(&sZ[0][0])[tid] = v;
    }
    __syncthreads();
    float acc[8];
#pragma unroll
    for (int mm = 0; mm < 8; ++mm) acc[mm] = 0.f;
#pragma unroll 2
    for (int n = 0; n < 128; ++n) {
        float w = wv[(size_t)n * 2048 + l];
#pragma unroll
        for (int mm = 0; mm < 8; ++mm) acc[mm] += sZ[mm][n] * w;
    }
    float bvl = bv[l];
    int n16 = l >> 4, e = l & 15;
#pragma unroll
    for (int mm = 0; mm < 8; ++mm) {
        int row = m0 + mm;
        int b = row / T;
        int t = row - b * T;
        size_t idx = ((size_t)(b * 128 + n16) * T + t) * 16 + e;
        x[idx] += acc[mm] + bvl;
    }
}

// ---------------- final dec+out ----------------
__global__ __launch_bounds__(128) void k_final(const float* __restrict__ x,
                        const float* __restrict__ dec_w, const float* __restrict__ dec_b,
                        const float* __restrict__ out_w, const float* __restrict__ out_b,
                        float* __restrict__ out) {
    int n = blockIdx.x & 127;
    int b = blockIdx.x >> 7;
    const int T = 122;
    __shared__ float y[128];
    int tid = threadIdx.x;
    if (tid < T) {
        const float* xp = x + ((size_t)(b * 128 + n) * T + tid) * 16;
        const float* dw = dec_w + n * 16;
        float acc = dec_b[n];
#pragma unroll
        for (int e = 0; e < 16; ++e) acc += xp[e] * dw[e];
        y[tid] = acc;
    }
    __syncthreads();
    if (tid < 24) {
        float acc = out_b[tid];
#pragma unroll 2
        for (int t = 0; t < 122; ++t) acc += y[t] * out_w[t * 24 + tid];
        out[(b * 24 + tid) * 128 + n] = acc;
    }
}

extern "C" void kernel_launch(void* const* d_in, const int* in_sizes, int n_in,
                              void* d_out, int out_size, void* d_ws, size_t ws_size,
                              hipStream_t stream) {
    const float* x_in  = (const float*)d_in[0];
    const float* emb_w = (const float*)d_in[1];
    const float* emb_b = (const float*)d_in[2];
    const float* g0_wf = (const float*)d_in[3];
    const float* g0_bf = (const float*)d_in[4];
    const float* g0_wg = (const float*)d_in[5];
    const float* g0_bg = (const float*)d_in[6];
    const float* g0_ws = (const float*)d_in[7];
    const float* g0_bs = (const float*)d_in[8];
    const float* a0_wq = (const float*)d_in[9];
    const float* a0_bq = (const float*)d_in[10];
    const float* a0_wk = (const float*)d_in[11];
    const float* a0_bk = (const float*)d_in[12];
    const float* a0_wv = (const float*)d_in[13];
    const float* a0_bv = (const float*)d_in[14];
    const float* g1_wf = (const float*)d_in[15];
    const float* g1_bf = (const float*)d_in[16];
    const float* g1_wg = (const float*)d_in[17];
    const float* g1_bg = (const float*)d_in[18];
    const float* g1_ws = (const float*)d_in[19];
    const float* g1_bs = (const float*)d_in[20];
    const float* a1_wq = (const float*)d_in[21];
    const float* a1_bq = (const float*)d_in[22];
    const float* a1_wk = (const float*)d_in[23];
    const float* a1_bk = (const float*)d_in[24];
    const float* a1_wv = (const float*)d_in[25];
    const float* a1_bv = (const float*)d_in[26];
    const float* dec_w = (const float*)d_in[27];
    const float* dec_b = (const float*)d_in[28];
    const float* out_w = (const float*)d_in[29];
    const float* out_b = (const float*)d_in[30];

    float* wsf  = (float*)d_ws;
    float* buf0 = wsf;                        // 1048576 (embed out; later reused as Z)
    float* buf1 = buf0 + 4 * 128 * 128 * 16;  // 1032192
    float* buf2 = buf1 + 4 * 128 * 126 * 16;  // 999424
    float* A0   = buf2 + 4 * 128 * 122 * 16;  // 16384
    float* A1   = A0 + 128 * 128;             // 16384
    float* uvc0 = A1 + 128 * 128;             // 257
    float* uvc1 = uvc0 + 257;                 // 257
    unsigned short* Wp0 = (unsigned short*)(uvc1 + 257);  // 256*256 bf16
    unsigned short* Wp1 = Wp0 + 256 * 256;                // 256*256 bf16
    float* Z    = buf0;                       // alias: buf0 dead after gated0 consumes it

    // precompute: attention A/uvc + packed gated weights
    k_zero<<<32, 256, 0, stream>>>(A0, 2 * 128 * 128 / 4);   // zeros A0 and A1 (contiguous)
    k_gemm_aat<<<256, 256, 0, stream>>>(a0_wq, a0_wk, A0);
    k_gemm_aat<<<256, 256, 0, stream>>>(a1_wq, a1_wk, A1);
    k_uvc<<<128, 64, 0, stream>>>(a0_wq, a0_bq, a0_wk, a0_bk, uvc0);
    k_uvc<<<128, 64, 0, stream>>>(a1_wq, a1_bq, a1_wk, a1_bk, uvc1);
    k_wpack<<<32, 256, 0, stream>>>(g0_wf, g0_wg, Wp0);
    k_wpack<<<32, 256, 0, stream>>>(g1_wf, g1_wg, Wp1);

    k_embed<<<4096, 256, 0, stream>>>(x_in, emb_w, emb_b, buf0);

    // layer 0: T=128 -> S=126
    k_gated_mfma<<<4 * 126, 64, 0, stream>>>(buf0, 128, 126, 2, Wp0, g0_bf, g0_bg, buf1);
    k_gated_res<<<4 * 128, 256, 0, stream>>>(buf0, 128, 126, g0_ws, g0_bs, buf1);
    k_attn_score<<<4 * 126, 256, 0, stream>>>(buf1, 126, A0, uvc0, Z);
    k_attn_out<<<(4 * 126 / 8) * 8, 256, 0, stream>>>(buf1, 126, Z, a0_wv, a0_bv);

    // layer 1: T=126 -> S=122
    k_gated_mfma<<<4 * 122, 64, 0, stream>>>(buf1, 126, 122, 4, Wp1, g1_bf, g1_bg, buf2);
    k_gated_res<<<4 * 128, 256, 0, stream>>>(buf1, 126, 122, g1_ws, g1_bs, buf2);
    k_attn_score<<<4 * 122, 256, 0, stream>>>(buf2, 122, A1, uvc1, Z);
    k_attn_out<<<(4 * 122 / 8) * 8, 256, 0, stream>>>(buf2, 122, Z, a1_wv, a1_bv);

    k_final<<<512, 128, 0, stream>>>(buf2, dec_w, dec_b, out_w, out_b, (float*)d_out);
}

// Round 8
// 270.141 us; speedup vs baseline: 3.4951x; 1.2869x over previous
//
#include <hip/hip_runtime.h>
#include <math.h>

// Shapes: B=4, T_LEN=128, W_DIM=128 (N), EMB=16 (E), OUT_DIM=24, DILS=(2,4)
// L = 2048, T_FINAL = 122.
// Activation layout: x[b][n][t][e] contiguous as ((b*128+n)*T+t)*16+e.

typedef __attribute__((ext_vector_type(8))) short bf16x8;
typedef __attribute__((ext_vector_type(4))) float f32x4;
typedef unsigned short ushort_t;

__device__ inline short f2bf(float x) {   // RNE fp32 -> bf16 bits
    union { float f; unsigned u; } v; v.f = x;
    unsigned r = v.u + 0x7FFFu + ((v.u >> 16) & 1u);
    return (short)(r >> 16);
}
__device__ inline float bf2f(ushort_t b) {
    union { unsigned u; float f; } v; v.u = ((unsigned)b) << 16; return v.f;
}

// ---------------- embed ----------------
__global__ __launch_bounds__(256) void k_embed(const float* __restrict__ x_in,
                        const float* __restrict__ emb_w,
                        const float* __restrict__ emb_b, float* __restrict__ out) {
    int idx = blockIdx.x * 256 + threadIdx.x;
    if (idx >= 4 * 128 * 128 * 16) return;
    int e = idx & 15;
    int t = (idx >> 4) & 127;
    int n = (idx >> 11) & 127;
    int b = idx >> 18;
    const float* row = x_in + (b * 128 + t) * 131;
    float val = row[n];
    float f0 = row[128], f1 = row[129], f2 = row[130];
    out[idx] = val * emb_w[e] + f0 * emb_w[16 + e] + f1 * emb_w[32 + e]
             + f2 * emb_w[48 + e] + emb_b[e];
}

// ---------------- zero ----------------
__global__ __launch_bounds__(256) void k_zero(float* __restrict__ p, int n4) {
    int i = blockIdx.x * 256 + threadIdx.x;
    if (i < n4) reinterpret_cast<float4*>(p)[i] = make_float4(0.f, 0.f, 0.f, 0.f);
}

// ---------------- A = Wq * Wk^T (128x128, K=2048), K-split with atomics ----
__global__ __launch_bounds__(256) void k_gemm_aat(const float* __restrict__ wq,
                                                  const float* __restrict__ wk,
                                                  float* __restrict__ A) {
    __shared__ float sq[32][129];
    __shared__ float sk[32][129];
    int bid = blockIdx.x;
    int it = bid & 3, jt = (bid >> 2) & 3, kc = bid >> 4;
    int i0 = it * 32, j0 = jt * 32, k0 = kc * 128;
    int tid = threadIdx.x;
    int row = tid >> 3, cl = tid & 7;
#pragma unroll
    for (int h = 0; h < 4; ++h) {
        int kk = (cl + 8 * h) * 4;
        float4 q = *reinterpret_cast<const float4*>(wq + (size_t)(i0 + row) * 2048 + k0 + kk);
        float4 k = *reinterpret_cast<const float4*>(wk + (size_t)(j0 + row) * 2048 + k0 + kk);
        sq[row][kk] = q.x; sq[row][kk + 1] = q.y; sq[row][kk + 2] = q.z; sq[row][kk + 3] = q.w;
        sk[row][kk] = k.x; sk[row][kk + 1] = k.y; sk[row][kk + 2] = k.z; sk[row][kk + 3] = k.w;
    }
    __syncthreads();
    int ti = tid >> 4, tj = tid & 15;
    int i = 2 * ti, j = 2 * tj;
    float a00 = 0.f, a01 = 0.f, a10 = 0.f, a11 = 0.f;
#pragma unroll 4
    for (int k = 0; k < 128; ++k) {
        float q0 = sq[i][k], q1 = sq[i + 1][k];
        float k0v = sk[j][k], k1v = sk[j + 1][k];
        a00 += q0 * k0v; a01 += q0 * k1v; a10 += q1 * k0v; a11 += q1 * k1v;
    }
    atomicAdd(&A[(i0 + i) * 128 + j0 + j], a00);
    atomicAdd(&A[(i0 + i) * 128 + j0 + j + 1], a01);
    atomicAdd(&A[(i0 + i + 1) * 128 + j0 + j], a10);
    atomicAdd(&A[(i0 + i + 1) * 128 + j0 + j + 1], a11);
}

// ---------------- uvc: u=Wq·bk, v=Wk·bq, c=bq·bk ----------------
__global__ __launch_bounds__(64) void k_uvc(const float* __restrict__ wq,
                                            const float* __restrict__ bq,
                                            const float* __restrict__ wk,
                                            const float* __restrict__ bk,
                                            float* __restrict__ uvc) {
    int i = blockIdx.x;
    int lane = threadIdx.x;
    float u = 0.f, v = 0.f, c = 0.f;
#pragma unroll
    for (int h = 0; h < 8; ++h) {
        int l0 = (lane + 64 * h) * 4;
        float4 q = *reinterpret_cast<const float4*>(wq + (size_t)i * 2048 + l0);
        float4 k = *reinterpret_cast<const float4*>(wk + (size_t)i * 2048 + l0);
        float4 bkv = *reinterpret_cast<const float4*>(bk + l0);
        float4 bqv = *reinterpret_cast<const float4*>(bq + l0);
        u += q.x * bkv.x + q.y * bkv.y + q.z * bkv.z + q.w * bkv.w;
        v += k.x * bqv.x + k.y * bqv.y + k.z * bqv.z + k.w * bqv.w;
        if (i == 0) c += bqv.x * bkv.x + bqv.y * bkv.y + bqv.z * bkv.z + bqv.w * bkv.w;
    }
#pragma unroll
    for (int off = 32; off > 0; off >>= 1) {
        u += __shfl_down(u, off);
        v += __shfl_down(v, off);
        if (i == 0) c += __shfl_down(c, off);
    }
    if (lane == 0) {
        uvc[i] = u;
        uvc[128 + i] = v;
        if (i == 0) uvc[256] = c;
    }
}

// ---------------- gated weight pack (bf16) ----------------
__global__ __launch_bounds__(256) void k_wpack(const float* __restrict__ wf,
                                               const float* __restrict__ wg,
                                               ushort_t* __restrict__ Wp) {
    int gid = blockIdx.x * 256 + threadIdx.x;   // 8192 = 256 m * 32 kgroups
    int m = gid >> 5, kg = gid & 31;
    const float* src = (m < 128 ? wf + (size_t)m * 256 : wg + (size_t)(m - 128) * 256) + kg * 8;
    float4 a = *reinterpret_cast<const float4*>(src);
    float4 b = *reinterpret_cast<const float4*>(src + 4);
    bf16x8 o;
    o[0] = f2bf(a.x); o[1] = f2bf(a.y); o[2] = f2bf(a.z); o[3] = f2bf(a.w);
    o[4] = f2bf(b.x); o[5] = f2bf(b.y); o[6] = f2bf(b.z); o[7] = f2bf(b.w);
    *reinterpret_cast<bf16x8*>(Wp + (size_t)m * 256 + kg * 8) = o;
}

// ---------------- per-layer weight packs: wvT / At_ext / wsT ----------------
// bid<128: wvT[l][k]=wv[k][l] via LDS transpose (tile 32k x 64l)
// 128<=bid<200: At_ext[i][k]: i<128 -> A[k][i]; i==128 -> u[k]; i==129 -> v[k]; else 0  (144x128)
// 200<=bid<264: wsT[s][t] = ws[t*S+s] padded to 128x128
__global__ __launch_bounds__(256) void k_packw(const float* __restrict__ A,
                                               const float* __restrict__ uvc,
                                               const float* __restrict__ wv,
                                               const float* __restrict__ ws,
                                               int Tw, int S,
                                               ushort_t* __restrict__ At,
                                               ushort_t* __restrict__ wvT,
                                               ushort_t* __restrict__ wsT) {
    int bid = blockIdx.x, tid = threadIdx.x;
    if (bid < 128) {
        __shared__ float tile[32][65];
        int kt = bid & 3, lt = bid >> 2;
        int k0 = kt * 32, l0 = lt * 64;
        int r = tid >> 6, c = tid & 63;
#pragma unroll
        for (int rr = r; rr < 32; rr += 4)
            tile[rr][c] = wv[(size_t)(k0 + rr) * 2048 + l0 + c];
        __syncthreads();
        int cc0 = tid >> 5, rr2 = tid & 31;
#pragma unroll
        for (int cc = cc0; cc < 64; cc += 8)
            wvT[(size_t)(l0 + cc) * 128 + k0 + rr2] = (ushort_t)f2bf(tile[rr2][cc]);
    } else if (bid < 200) {
        int gid = (bid - 128) * 256 + tid;   // 0..18431
        int i = gid >> 7, k = gid & 127;
        float val;
        if (i < 128) val = A[k * 128 + i];
        else if (i == 128) val = uvc[k];
        else if (i == 129) val = uvc[128 + k];
        else val = 0.f;
        At[(size_t)i * 128 + k] = (ushort_t)f2bf(val);
    } else {
        int gid = (bid - 200) * 256 + tid;   // 0..16383
        int s = gid >> 7, t = gid & 127;
        float val = (t < Tw && s < S) ? ws[t * S + s] : 0.f;
        wsT[(size_t)s * 128 + t] = (ushort_t)f2bf(val);
    }
}

// ---------------- pack xT[b,c,e,t(pad128)] bf16 from x[b,c,t,e] ----------------
__global__ __launch_bounds__(128) void k_pack_ncet(const float* __restrict__ x, int T,
                                                   ushort_t* __restrict__ xT) {
    int bc = blockIdx.x;          // 0..511
    int t = threadIdx.x;          // 0..127
    float v[16];
    if (t < T) {
        const float4* p = reinterpret_cast<const float4*>(x + ((size_t)bc * T + t) * 16);
        float4 a = p[0], b = p[1], c = p[2], d = p[3];
        v[0]=a.x; v[1]=a.y; v[2]=a.z; v[3]=a.w; v[4]=b.x; v[5]=b.y; v[6]=b.z; v[7]=b.w;
        v[8]=c.x; v[9]=c.y; v[10]=c.z; v[11]=c.w; v[12]=d.x; v[13]=d.y; v[14]=d.z; v[15]=d.w;
    } else {
#pragma unroll
        for (int e = 0; e < 16; ++e) v[e] = 0.f;
    }
#pragma unroll
    for (int e = 0; e < 16; ++e)
        xT[((size_t)bc * 16 + e) * 128 + t] = (ushort_t)f2bf(v[e]);
}

// ---------------- pack Xt[tau, e, n] bf16 from x[b,n,t,e] ----------------
__global__ __launch_bounds__(128) void k_pack_xt(const float* __restrict__ x, int T,
                                                 ushort_t* __restrict__ Xt) {
    int tau = blockIdx.x;
    int b = tau / T, t = tau - b * T;
    int n = threadIdx.x;
    const float4* p = reinterpret_cast<const float4*>(x + ((size_t)(b * 128 + n) * T + t) * 16);
    float4 a = p[0], bb = p[1], c = p[2], d = p[3];
    float v[16] = {a.x,a.y,a.z,a.w, bb.x,bb.y,bb.z,bb.w, c.x,c.y,c.z,c.w, d.x,d.y,d.z,d.w};
#pragma unroll
    for (int e = 0; e < 16; ++e)
        Xt[(size_t)tau * 2048 + e * 128 + n] = (ushort_t)f2bf(v[e]);
}

// ---------------- gated f/g via MFMA (unchanged) ----------------
__global__ __launch_bounds__(64) void k_gated_mfma(const float* __restrict__ x,
                        int T, int S, int d,
                        const ushort_t* __restrict__ Wp,
                        const float* __restrict__ bf, const float* __restrict__ bg,
                        float* __restrict__ out) {
    int s = blockIdx.x % S;
    int b = blockIdx.x / S;
    int lane = threadIdx.x;
    int e = lane & 15, kh = lane >> 4;
    const float* xb = x + (size_t)b * 128 * T * 16;

    f32x4 acc[16];
#pragma unroll
    for (int i = 0; i < 16; ++i) acc[i] = (f32x4){0.f, 0.f, 0.f, 0.f};

#pragma unroll
    for (int kc = 0; kc < 8; ++kc) {
        bf16x8 aF;
#pragma unroll
        for (int j = 0; j < 8; ++j) {
            int k = kc * 32 + kh * 8 + j;
            int i = k >> 1, tap = k & 1;
            float v = xb[((size_t)i * T + s + tap * d) * 16 + e];
            aF[j] = f2bf(v);
        }
#pragma unroll
        for (int fn = 0; fn < 16; ++fn) {
            int m = fn * 16 + e;
            bf16x8 bF = *reinterpret_cast<const bf16x8*>(Wp + (size_t)m * 256 + kc * 32 + kh * 8);
            acc[fn] = __builtin_amdgcn_mfma_f32_16x16x32_bf16(aF, bF, acc[fn], 0, 0, 0);
        }
    }
    int e0 = kh * 4;
#pragma unroll
    for (int fn = 0; fn < 8; ++fn) {
        int c = fn * 16 + e;
        float bfv = bf[c], bgv = bg[c];
        float4 o;
        float fv, gv;
        fv = acc[fn][0] + bfv; gv = acc[fn + 8][0] + bgv; o.x = tanhf(fv) / (1.f + expf(-gv));
        fv = acc[fn][1] + bfv; gv = acc[fn + 8][1] + bgv; o.y = tanhf(fv) / (1.f + expf(-gv));
        fv = acc[fn][2] + bfv; gv = acc[fn + 8][2] + bgv; o.z = tanhf(fv) / (1.f + expf(-gv));
        fv = acc[fn][3] + bfv; gv = acc[fn + 8][3] + bgv; o.w = tanhf(fv) / (1.f + expf(-gv));
        *reinterpret_cast<float4*>(out + (((size_t)(b * 128 + c)) * S + s) * 16 + e0) = o;
    }
}

// ---------------- res via MFMA: out[bc,s,e] += sum_t xT[bc,e,t]*wsT[s,t] + bs[s] ----
__global__ __launch_bounds__(256) void k_resmm(const ushort_t* __restrict__ xT,
                                               const ushort_t* __restrict__ wsT,
                                               const float* __restrict__ bs,
                                               float* __restrict__ out, int S) {
    int bc = blockIdx.x;
    int tid = threadIdx.x;
    int w = tid >> 6, lane = tid & 63;
    int e16 = lane & 15, kh = lane >> 4;
    bf16x8 bx[4];
#pragma unroll
    for (int kf = 0; kf < 4; ++kf)
        bx[kf] = *reinterpret_cast<const bf16x8*>(xT + ((size_t)bc * 16 + e16) * 128 + kf * 32 + kh * 8);
    f32x4 acc0 = (f32x4){0.f,0.f,0.f,0.f}, acc1 = acc0;
#pragma unroll
    for (int kf = 0; kf < 4; ++kf) {
        bf16x8 a0 = *reinterpret_cast<const bf16x8*>(wsT + ((size_t)(w * 16) + e16) * 128 + kf * 32 + kh * 8);
        bf16x8 a1 = *reinterpret_cast<const bf16x8*>(wsT + ((size_t)((w + 4) * 16) + e16) * 128 + kf * 32 + kh * 8);
        acc0 = __builtin_amdgcn_mfma_f32_16x16x32_bf16(a0, bx[kf], acc0, 0, 0, 0);
        acc1 = __builtin_amdgcn_mfma_f32_16x16x32_bf16(a1, bx[kf], acc1, 0, 0, 0);
    }
#pragma unroll
    for (int reg = 0; reg < 4; ++reg) {
        int s0 = w * 16 + kh * 4 + reg;
        if (s0 < S) out[((size_t)bc * S + s0) * 16 + e16] += acc0[reg] + bs[s0];
        int s1 = (w + 4) * 16 + kh * 4 + reg;
        if (s1 < S) out[((size_t)bc * S + s1) * 16 + e16] += acc1[reg] + bs[s1];
    }
}

// ---------------- Y GEMM: Ybf[tau*16+e][i] = sum_n Xt[tau,e,n]*At[i,n]  (i<144) ----
__global__ __launch_bounds__(64) void k_ymm(const ushort_t* __restrict__ Xt,
                                            const ushort_t* __restrict__ At,
                                            ushort_t* __restrict__ Y) {
    int tau = blockIdx.x;
    int lane = threadIdx.x;
    int e16 = lane & 15, kh = lane >> 4;
    bf16x8 a[4];
#pragma unroll
    for (int kf = 0; kf < 4; ++kf)
        a[kf] = *reinterpret_cast<const bf16x8*>(Xt + (size_t)tau * 2048 + e16 * 128 + kf * 32 + kh * 8);
    f32x4 acc[9];
#pragma unroll
    for (int i = 0; i < 9; ++i) acc[i] = (f32x4){0.f,0.f,0.f,0.f};
#pragma unroll
    for (int nf = 0; nf < 9; ++nf)
#pragma unroll
        for (int kf = 0; kf < 4; ++kf) {
            bf16x8 b = *reinterpret_cast<const bf16x8*>(At + ((size_t)(nf * 16) + e16) * 128 + kf * 32 + kh * 8);
            acc[nf] = __builtin_amdgcn_mfma_f32_16x16x32_bf16(a[kf], b, acc[nf], 0, 0, 0);
        }
#pragma unroll
    for (int nf = 0; nf < 9; ++nf)
#pragma unroll
        for (int reg = 0; reg < 4; ++reg)
            Y[(size_t)(tau * 16 + kh * 4 + reg) * 144 + nf * 16 + e16] = (ushort_t)f2bf(acc[nf][reg]);
}

// ---------------- scores+softmax+z: per (b,t) wave -> Zbf[tau][n] ----------------
__global__ __launch_bounds__(256) void k_smz(const ushort_t* __restrict__ Y,
                                             const ushort_t* __restrict__ Xt,
                                             const float* __restrict__ x,
                                             const float* __restrict__ uvc,
                                             int T, ushort_t* __restrict__ Z) {
    __shared__ float sabar[4][16];
    int tid = threadIdx.x;
    int w = tid >> 6, lane = tid & 63;
    int tau = blockIdx.x * 4 + w;
    int e16 = lane & 15, kh = lane >> 4;
    int b = tau / T, t = tau - b * T;
    f32x4 acc = (f32x4){0.f,0.f,0.f,0.f};
#pragma unroll
    for (int kf = 0; kf < 4; ++kf) {
        bf16x8 aY = *reinterpret_cast<const bf16x8*>(Y + (size_t)(tau * 16 + e16) * 144 + kf * 32 + kh * 8);
        bf16x8 bX = *reinterpret_cast<const bf16x8*>(Xt + (size_t)tau * 2048 + e16 * 128 + kf * 32 + kh * 8);
        acc = __builtin_amdgcn_mfma_f32_16x16x32_bf16(aY, bX, acc, 0, 0, 0);
    }
    float c0 = uvc[256];
    float vfv = bf2f(Y[(size_t)(tau * 16 + e16) * 144 + 129]);
    const float scale = 0.022097086912079608f;  // 1/sqrt(2048)
    float alpha[4];
    float absum = 0.f;
#pragma unroll
    for (int reg = 0; reg < 4; ++reg) {
        int er = kh * 4 + reg;
        float ue = bf2f(Y[(size_t)(tau * 16 + er) * 144 + 128]);
        float s = (acc[reg] + ue + vfv + c0) * scale;
        float m = s;
        m = fmaxf(m, __shfl_xor(m, 1));
        m = fmaxf(m, __shfl_xor(m, 2));
        m = fmaxf(m, __shfl_xor(m, 4));
        m = fmaxf(m, __shfl_xor(m, 8));
        float p = __expf(s - m);
        float ss = p;
        ss += __shfl_xor(ss, 1);
        ss += __shfl_xor(ss, 2);
        ss += __shfl_xor(ss, 4);
        ss += __shfl_xor(ss, 8);
        alpha[reg] = p / ss;
        absum += alpha[reg];
    }
    // abar[f = e16] = (1/16) * sum over all e
    absum += __shfl_xor(absum, 16);
    absum += __shfl_xor(absum, 32);
    absum *= (1.f / 16.f);
    if (kh == 0) sabar[w][e16] = absum;
    __syncthreads();
    // z[n] = sum_f abar[f] * x[b,n,t,f]
#pragma unroll
    for (int h = 0; h < 2; ++h) {
        int n = lane + h * 64;
        const float4* xp = reinterpret_cast<const float4*>(x + ((size_t)(b * 128 + n) * T + t) * 16);
        float4 r0 = xp[0], r1 = xp[1], r2 = xp[2], r3 = xp[3];
        float z = r0.x*sabar[w][0] + r0.y*sabar[w][1] + r0.z*sabar[w][2] + r0.w*sabar[w][3]
                + r1.x*sabar[w][4] + r1.y*sabar[w][5] + r1.z*sabar[w][6] + r1.w*sabar[w][7]
                + r2.x*sabar[w][8] + r2.y*sabar[w][9] + r2.z*sabar[w][10] + r2.w*sabar[w][11]
                + r3.x*sabar[w][12] + r3.y*sabar[w][13] + r3.z*sabar[w][14] + r3.w*sabar[w][15];
        Z[(size_t)tau * 128 + n] = (ushort_t)f2bf(z);
    }
}

// ---------------- attn out GEMM: x[tau, l] += Z[tau,:]·wvT[l,:] + bv[l] ----------------
__global__ __launch_bounds__(256) void k_zmm(const ushort_t* __restrict__ Z,
                                             const ushort_t* __restrict__ wvT,
                                             const float* __restrict__ bv,
                                             float* __restrict__ x, int T, int BT) {
    int bid = blockIdx.x;
    int mt = bid >> 5, ng = bid & 31;
    int tid = threadIdx.x;
    int w = tid >> 6, lane = tid & 63;
    int e16 = lane & 15, kh = lane >> 4;
    int nf = ng * 4 + w;
    int l = nf * 16 + e16;
    f32x4 acc = (f32x4){0.f,0.f,0.f,0.f};
#pragma unroll
    for (int kf = 0; kf < 4; ++kf) {
        bf16x8 aZ = *reinterpret_cast<const bf16x8*>(Z + (size_t)(mt * 16 + e16) * 128 + kf * 32 + kh * 8);
        bf16x8 bW = *reinterpret_cast<const bf16x8*>(wvT + (size_t)l * 128 + kf * 32 + kh * 8);
        acc = __builtin_amdgcn_mfma_f32_16x16x32_bf16(aZ, bW, acc, 0, 0, 0);
    }
    float bvl = bv[l];
    int n16 = l >> 4, e = l & 15;
#pragma unroll
    for (int reg = 0; reg < 4; ++reg) {
        int tau = mt * 16 + kh * 4 + reg;
        if (tau < BT) {
            int b = tau / T, t = tau - b * T;
            size_t idx = ((size_t)(b * 128 + n16) * T + t) * 16 + e;
            x[idx] += acc[reg] + bvl;
        }
    }
}

// ---------------- final dec+out ----------------
__global__ __launch_bounds__(128) void k_final(const float* __restrict__ x,
                        const float* __restrict__ dec_w, const float* __restrict__ dec_b,
                        const float* __restrict__ out_w, const float* __restrict__ out_b,
                        float* __restrict__ out) {
    int n = blockIdx.x & 127;
    int b = blockIdx.x >> 7;
    const int T = 122;
    __shared__ float y[128];
    int tid = threadIdx.x;
    if (tid < T) {
        const float* xp = x + ((size_t)(b * 128 + n) * T + tid) * 16;
        const float* dw = dec_w + n * 16;
        float acc = dec_b[n];
#pragma unroll
        for (int e = 0; e < 16; ++e) acc += xp[e] * dw[e];
        y[tid] = acc;
    }
    __syncthreads();
    if (tid < 24) {
        float acc = out_b[tid];
#pragma unroll 2
        for (int t = 0; t < 122; ++t) acc += y[t] * out_w[t * 24 + tid];
        out[(b * 24 + tid) * 128 + n] = acc;
    }
}

extern "C" void kernel_launch(void* const* d_in, const int* in_sizes, int n_in,
                              void* d_out, int out_size, void* d_ws, size_t ws_size,
                              hipStream_t stream) {
    const float* x_in  = (const float*)d_in[0];
    const float* emb_w = (const float*)d_in[1];
    const float* emb_b = (const float*)d_in[2];
    const float* g0_wf = (const float*)d_in[3];
    const float* g0_bf = (const float*)d_in[4];
    const float* g0_wg = (const float*)d_in[5];
    const float* g0_bg = (const float*)d_in[6];
    const float* g0_ws = (const float*)d_in[7];
    const float* g0_bs = (const float*)d_in[8];
    const float* a0_wq = (const float*)d_in[9];
    const float* a0_bq = (const float*)d_in[10];
    const float* a0_wk = (const float*)d_in[11];
    const float* a0_bk = (const float*)d_in[12];
    const float* a0_wv = (const float*)d_in[13];
    const float* a0_bv = (const float*)d_in[14];
    const float* g1_wf = (const float*)d_in[15];
    const float* g1_bf = (const float*)d_in[16];
    const float* g1_wg = (const float*)d_in[17];
    const float* g1_bg = (const float*)d_in[18];
    const float* g1_ws = (const float*)d_in[19];
    const float* g1_bs = (const float*)d_in[20];
    const float* a1_wq = (const float*)d_in[21];
    const float* a1_bq = (const float*)d_in[22];
    const float* a1_wk = (const float*)d_in[23];
    const float* a1_bk = (const float*)d_in[24];
    const float* a1_wv = (const float*)d_in[25];
    const float* a1_bv = (const float*)d_in[26];
    const float* dec_w = (const float*)d_in[27];
    const float* dec_b = (const float*)d_in[28];
    const float* out_w = (const float*)d_in[29];
    const float* out_b = (const float*)d_in[30];

    float* wsf = (float*)d_ws;
    size_t off = 0;
    auto alloc = [&](size_t n) { float* p = wsf + off; off += (n + 15) & ~(size_t)15; return p; };

    float* buf0 = alloc(4 * 128 * 128 * 16);
    float* buf1 = alloc(4 * 128 * 126 * 16);
    float* buf2 = alloc(4 * 128 * 122 * 16);
    float* A0   = alloc(2 * 128 * 128);      // A0 and A1 contiguous (k_zero covers both)
    float* A1   = A0 + 128 * 128;
    float* uvc0 = alloc(320);
    float* uvc1 = alloc(320);
    ushort_t* Wp0  = (ushort_t*)alloc(32768);
    ushort_t* Wp1  = (ushort_t*)alloc(32768);
    ushort_t* At0  = (ushort_t*)alloc(9216);    // 144*128 bf16
    ushort_t* At1  = (ushort_t*)alloc(9216);
    ushort_t* wvT0 = (ushort_t*)alloc(131072);  // 2048*128 bf16
    ushort_t* wvT1 = (ushort_t*)alloc(131072);
    ushort_t* wsT0 = (ushort_t*)alloc(8192);    // 128*128 bf16
    ushort_t* wsT1 = (ushort_t*)alloc(8192);
    ushort_t* xTbf = (ushort_t*)alloc(524288);  // 512*16*128 bf16
    ushort_t* Xtbf = (ushort_t*)alloc(524288);  // 512*2048 bf16
    ushort_t* Ybf  = (ushort_t*)alloc(589824);  // 8192*144 bf16
    ushort_t* Zbf  = (ushort_t*)alloc(32768);   // 512*128 bf16

    // ---- precompute ----
    k_zero<<<32, 256, 0, stream>>>(A0, 2 * 128 * 128 / 4);
    k_gemm_aat<<<256, 256, 0, stream>>>(a0_wq, a0_wk, A0);
    k_gemm_aat<<<256, 256, 0, stream>>>(a1_wq, a1_wk, A1);
    k_uvc<<<128, 64, 0, stream>>>(a0_wq, a0_bq, a0_wk, a0_bk, uvc0);
    k_uvc<<<128, 64, 0, stream>>>(a1_wq, a1_bq, a1_wk, a1_bk, uvc1);
    k_wpack<<<32, 256, 0, stream>>>(g0_wf, g0_wg, Wp0);
    k_wpack<<<32, 256, 0, stream>>>(g1_wf, g1_wg, Wp1);
    k_packw<<<264, 256, 0, stream>>>(A0, uvc0, a0_wv, g0_ws, 128, 126, At0, wvT0, wsT0);
    k_packw<<<264, 256, 0, stream>>>(A1, uvc1, a1_wv, g1_ws, 126, 122, At1, wvT1, wsT1);

    k_embed<<<4096, 256, 0, stream>>>(x_in, emb_w, emb_b, buf0);

    // ---- layer 0: T=128 -> S=126, BT=504 ----
    k_pack_ncet<<<512, 128, 0, stream>>>(buf0, 128, xTbf);
    k_gated_mfma<<<4 * 126, 64, 0, stream>>>(buf0, 128, 126, 2, Wp0, g0_bf, g0_bg, buf1);
    k_resmm<<<512, 256, 0, stream>>>(xTbf, wsT0, g0_bs, buf1, 126);
    k_pack_xt<<<504, 128, 0, stream>>>(buf1, 126, Xtbf);
    k_ymm<<<504, 64, 0, stream>>>(Xtbf, At0, Ybf);
    k_smz<<<126, 256, 0, stream>>>(Ybf, Xtbf, buf1, uvc0, 126, Zbf);
    k_zmm<<<32 * 32, 256, 0, stream>>>(Zbf, wvT0, a0_bv, buf1, 126, 504);

    // ---- layer 1: T=126 -> S=122, BT=488 ----
    k_pack_ncet<<<512, 128, 0, stream>>>(buf1, 126, xTbf);
    k_gated_mfma<<<4 * 122, 64, 0, stream>>>(buf1, 126, 122, 4, Wp1, g1_bf, g1_bg, buf2);
    k_resmm<<<512, 256, 0, stream>>>(xTbf, wsT1, g1_bs, buf2, 122);
    k_pack_xt<<<488, 128, 0, stream>>>(buf2, 122, Xtbf);
    k_ymm<<<488, 64, 0, stream>>>(Xtbf, At1, Ybf);
    k_smz<<<122, 256, 0, stream>>>(Ybf, Xtbf, buf2, uvc1, 122, Zbf);
    k_zmm<<<31 * 32, 256, 0, stream>>>(Zbf, wvT1, a1_bv, buf2, 122, 488);

    k_final<<<512, 128, 0, stream>>>(buf2, dec_w, dec_b, out_w, out_b, (float*)d_out);
}